// Round 2
// baseline (926.365 us; speedup 1.0000x reference)
//
#include <hip/hip_runtime.h>
#include <hip/hip_bf16.h>

typedef __attribute__((ext_vector_type(8))) short short8;   // 8 bf16 in 4 VGPRs
typedef __attribute__((ext_vector_type(4))) float f32x4;

#define N_HEAD 16
#define DMODEL 1024
#define LV 2048
#define LQ 2048
#define BATCH 2
#define HEAD_DIM 64

__device__ inline ushort f2bf(float f) {
    union { float f; unsigned u; } v; v.f = f;
    unsigned r = v.u + 0x7fffu + ((v.u >> 16) & 1u);   // RNE
    return (ushort)(r >> 16);
}
__device__ inline float bf2f(ushort h) {
    union { unsigned u; float f; } v; v.u = ((unsigned)h) << 16;
    return v.f;
}

// ---------------- cast f32 -> bf16 (same layout) ----------------
__global__ __launch_bounds__(256) void cast_bf16(const float* __restrict__ src,
                                                 ushort* __restrict__ dst, int n) {
    int i = (blockIdx.x * 256 + threadIdx.x) * 4;
    if (i < n) {
        float4 v = *(const float4*)(src + i);
        ushort4 o;
        o.x = f2bf(v.x); o.y = f2bf(v.y); o.z = f2bf(v.z); o.w = f2bf(v.w);
        *(ushort4*)(dst + i) = o;
    }
}

// ---------------- transpose + cast: src[z][R][C] f32 -> dst[z][C][R] bf16 ----
__global__ __launch_bounds__(256) void transpose_cast(const float* __restrict__ src,
                                                      ushort* __restrict__ dst,
                                                      int R, int C) {
    __shared__ float t[32][33];
    size_t zoff = (size_t)blockIdx.z * R * C;
    int c0 = blockIdx.x * 32, r0 = blockIdx.y * 32;
    int tx = threadIdx.x, ty = threadIdx.y;
#pragma unroll
    for (int i = 0; i < 4; ++i)
        t[ty + i * 8][tx] = src[zoff + (size_t)(r0 + ty + i * 8) * C + c0 + tx];
    __syncthreads();
#pragma unroll
    for (int i = 0; i < 4; ++i)
        dst[zoff + (size_t)(c0 + ty + i * 8) * R + r0 + tx] = f2bf(t[tx][ty + i * 8]);
}

// ---------------- batched GEMM: C[z] = (relu)(A[z] @ B[z]^T + bias) ----------
// A: M x K row-major (bf16), B: N x K row-major (bf16, i.e. B^T), per-z offsets.
// 128x128 tile, BK=32, 4 waves (2x2), 4x4 16x16x32 MFMA frags per wave.
template <bool RELU, bool OUT_BF16>
__global__ __launch_bounds__(256) void gemm128(
    const ushort* __restrict__ A, const ushort* __restrict__ B,
    void* __restrict__ Cout, const float* __restrict__ bias,
    int M, int N, int K,
    long sA_b, long sA_h, long sB_b, long sB_h, long sC_z, int ldc, long sBias_h)
{
    __shared__ ushort tileAB[2][2][128 * 32];   // [buf][A/B][row*32+col], 32 KiB

    const int z = blockIdx.z;
    const int b = z & 1;
    const int h = z >> 1;
    A += (size_t)b * sA_b + (size_t)h * sA_h;
    B += (size_t)b * sB_b + (size_t)h * sB_h;
    const float* biasp = bias ? bias + (size_t)h * sBias_h : nullptr;

    const int bm0 = blockIdx.y * 128;
    const int bn0 = blockIdx.x * 128;
    const int t = threadIdx.x;
    const int wid = t >> 6, lane = t & 63;
    const int wr = wid >> 1, wc = wid & 1;
    const int fr = lane & 15;        // frag row (A) / col (B,C)
    const int fq = lane >> 4;        // quad

    f32x4 acc[4][4];
#pragma unroll
    for (int m = 0; m < 4; ++m)
#pragma unroll
        for (int n = 0; n < 4; ++n)
#pragma unroll
            for (int j = 0; j < 4; ++j) acc[m][n][j] = 0.f;

    auto stage = [&](int buf, int kt) {
#pragma unroll
        for (int c = 0; c < 2; ++c) {
            int idx = c * 256 + t;               // 0..511  (each stages 8 bf16 = 16B)
            int row = idx >> 2;                  // 128 rows
            int col = (idx & 3) << 3;            // 0,8,16,24
            const ushort* ga = A + (size_t)(bm0 + row) * K + kt * 32 + col;
            __builtin_amdgcn_global_load_lds(
                (const __attribute__((address_space(1))) void*)ga,
                (__attribute__((address_space(3))) void*)&tileAB[buf][0][idx * 8],
                16, 0, 0);
            const ushort* gb = B + (size_t)(bn0 + row) * K + kt * 32 + col;
            __builtin_amdgcn_global_load_lds(
                (const __attribute__((address_space(1))) void*)gb,
                (__attribute__((address_space(3))) void*)&tileAB[buf][1][idx * 8],
                16, 0, 0);
        }
    };

    auto compute = [&](int buf) {
        const ushort* la = &tileAB[buf][0][(wr * 64 + fr) * 32 + fq * 8];
        const ushort* lb = &tileAB[buf][1][(wc * 64 + fr) * 32 + fq * 8];
        short8 af[4], bv[4];
#pragma unroll
        for (int m = 0; m < 4; ++m) af[m] = *(const short8*)(la + m * 512);
#pragma unroll
        for (int n = 0; n < 4; ++n) bv[n] = *(const short8*)(lb + n * 512);
#pragma unroll
        for (int m = 0; m < 4; ++m)
#pragma unroll
            for (int n = 0; n < 4; ++n)
                acc[m][n] = __builtin_amdgcn_mfma_f32_16x16x32_bf16(
                    af[m], bv[n], acc[m][n], 0, 0, 0);
    };

    const int nk = K >> 5;
    stage(0, 0);
    __syncthreads();
    for (int kt = 0; kt < nk; ++kt) {
        int cur = kt & 1;
        if (kt + 1 < nk) stage(cur ^ 1, kt + 1);
        compute(cur);
        __syncthreads();
    }

    // epilogue: C[row = m*16 + fq*4 + j][col = n*16 + fr]  (m89/m91-verified)
    const int row0 = bm0 + wr * 64;
    const int col0 = bn0 + wc * 64;
    ushort* cb = nullptr; float* cf = nullptr;
    if (OUT_BF16) cb = (ushort*)Cout + (size_t)z * sC_z;
    else          cf = (float*)Cout + (size_t)z * sC_z;
#pragma unroll
    for (int n = 0; n < 4; ++n) {
        int c = col0 + n * 16 + fr;
        float bvv = biasp ? biasp[c] : 0.f;
#pragma unroll
        for (int m = 0; m < 4; ++m) {
            int r = row0 + m * 16 + fq * 4;
#pragma unroll
            for (int j = 0; j < 4; ++j) {
                float val = acc[m][n][j] + bvv;
                if (RELU) val = fmaxf(val, 0.f);
                if (OUT_BF16) cb[(size_t)(r + j) * ldc + c] = f2bf(val);
                else          cf[(size_t)(r + j) * ldc + c] = val;
            }
        }
    }
}

// ---------------- in-place LayerNorm over last dim (1024) of agg bf16 --------
// gamma/beta already offset to the chunk's first head.
__global__ __launch_bounds__(256) void ln_kernel(ushort* __restrict__ agg,
                                                 const float* __restrict__ gamma,
                                                 const float* __restrict__ beta) {
    const int wid = threadIdx.x >> 6, lane = threadIdx.x & 63;
    const size_t row = (size_t)blockIdx.x * 4 + wid;      // rows over local z
    const int h = (int)(row >> 12);                       // local h = (row/2048)>>1
    ushort* p = agg + row * 1024 + lane * 16;
    short8 r0 = *(const short8*)p;
    short8 r1 = *(const short8*)(p + 8);
    float x[16];
#pragma unroll
    for (int j = 0; j < 8; ++j) { x[j] = bf2f((ushort)r0[j]); x[8 + j] = bf2f((ushort)r1[j]); }
    float s = 0.f, s2 = 0.f;
#pragma unroll
    for (int j = 0; j < 16; ++j) { s += x[j]; s2 += x[j] * x[j]; }
    for (int o = 1; o < 64; o <<= 1) {
        s  += __shfl_xor(s,  o, 64);
        s2 += __shfl_xor(s2, o, 64);
    }
    float mu  = s * (1.0f / 1024.0f);
    float var = s2 * (1.0f / 1024.0f) - mu * mu;
    float rs  = rsqrtf(fmaxf(var, 0.f) + 1e-5f);
    const float* g  = gamma + (size_t)h * 1024 + lane * 16;
    const float* bt = beta  + (size_t)h * 1024 + lane * 16;
    short8 o0, o1;
#pragma unroll
    for (int j = 0; j < 8; ++j) {
        o0[j] = (short)f2bf((x[j]     - mu) * rs * g[j]     + bt[j]);
        o1[j] = (short)f2bf((x[8 + j] - mu) * rs * g[8 + j] + bt[8 + j]);
    }
    *(short8*)p = o0;
    *(short8*)(p + 8) = o1;
}

// ---------------- projection: out[b][q][(h0+h)*64+e] = normed[z] @ WpT[h]^T + bp
// per wave: one 16-row m-tile, all 4 n-tiles (N=64), K=1024 from global (L2-hot).
__global__ __launch_bounds__(256) void proj_kernel(const ushort* __restrict__ normed,
                                                   const ushort* __restrict__ WpT,
                                                   const float* __restrict__ bp,
                                                   float* __restrict__ out,
                                                   int h_base) {
    const int z = blockIdx.y, b = z & 1, h = z >> 1;        // local h
    const int hg = h_base + h;                              // global h
    const int wid = threadIdx.x >> 6, lane = threadIdx.x & 63;
    const int fr = lane & 15, fq = lane >> 4;
    const int m0 = (blockIdx.x * 4 + wid) * 16;

    const ushort* Abase = normed + ((size_t)z * 2048 + m0 + fr) * 1024 + fq * 8;
    const ushort* Bbase = WpT + (size_t)hg * 64 * 1024 + (size_t)fr * 1024 + fq * 8;

    f32x4 acc[4];
#pragma unroll
    for (int n = 0; n < 4; ++n)
#pragma unroll
        for (int j = 0; j < 4; ++j) acc[n][j] = 0.f;

    for (int kt = 0; kt < 32; ++kt) {
        short8 a = *(const short8*)(Abase + kt * 32);
#pragma unroll
        for (int n = 0; n < 4; ++n) {
            short8 bb = *(const short8*)(Bbase + n * 16 * 1024 + kt * 32);
            acc[n] = __builtin_amdgcn_mfma_f32_16x16x32_bf16(a, bb, acc[n], 0, 0, 0);
        }
    }
#pragma unroll
    for (int n = 0; n < 4; ++n) {
        int c = hg * 64 + n * 16 + fr;
        float bvv = bp[hg * 64 + n * 16 + fr];
#pragma unroll
        for (int j = 0; j < 4; ++j)
            out[(size_t)b * 2048 * 1024 + (size_t)(m0 + fq * 4 + j) * 1024 + c] =
                acc[n][j] + bvv;
    }
}

extern "C" void kernel_launch(void* const* d_in, const int* in_sizes, int n_in,
                              void* d_out, int out_size, void* d_ws, size_t ws_size,
                              hipStream_t stream) {
    const float* v     = (const float*)d_in[0];
    const float* q     = (const float*)d_in[1];
    const float* Wa    = (const float*)d_in[2];
    const float* ba    = (const float*)d_in[3];
    const float* gamma = (const float*)d_in[4];
    const float* beta  = (const float*)d_in[5];
    const float* Wp    = (const float*)d_in[6];
    const float* bp    = (const float*)d_in[7];
    float* out = (float*)d_out;

    const size_t MB = 1ull << 20;
    // fixed buffers
    char* ws = (char*)d_ws;
    ushort* qbf = (ushort*)(ws);                 //  8 MiB
    ushort* vT  = (ushort*)(ws + 8 * MB);        //  8 MiB
    ushort* WpT = (ushort*)(ws + 16 * MB);       //  2 MiB
    // chunked region starts at 18 MiB: per head chunk of NH heads:
    //   WaT_c: NH*4 MiB, attn_c: NH*16 MiB, agg_c: NH*8 MiB  (total 28*NH MiB)
    int NH = 1;
    {
        const int cands[5] = {16, 8, 4, 2, 1};
        for (int i = 0; i < 5; ++i) {
            if ((size_t)(18 + 28 * cands[i]) * MB <= ws_size) { NH = cands[i]; break; }
        }
    }
    ushort* WaT_c  = (ushort*)(ws + 18 * MB);
    ushort* attn_c = (ushort*)(ws + (18 + (size_t)4 * NH) * MB);
    ushort* agg_c  = (ushort*)(ws + (18 + (size_t)20 * NH) * MB);

    dim3 tb(32, 8);
    // one-time prep
    cast_bf16<<<4096, 256, 0, stream>>>(q, qbf, BATCH * LQ * DMODEL);
    transpose_cast<<<dim3(DMODEL / 32, LV / 32, BATCH), tb, 0, stream>>>(v, vT, LV, DMODEL);
    transpose_cast<<<dim3(HEAD_DIM / 32, DMODEL / 32, N_HEAD), tb, 0, stream>>>(Wp, WpT, DMODEL, HEAD_DIM);

    for (int h0 = 0; h0 < N_HEAD; h0 += NH) {
        // transpose this chunk's Wa: [NH][D][LV] -> [NH][LV][D]
        transpose_cast<<<dim3(LV / 32, DMODEL / 32, NH), tb, 0, stream>>>(
            Wa + (size_t)h0 * DMODEL * LV, WaT_c, DMODEL, LV);

        // GEMM1: attn[z] = relu(q[b] @ WaT[h]^T + ba[h0+h]), M=2048 N=2048 K=1024
        gemm128<true, true><<<dim3(LV / 128, LQ / 128, NH * 2), 256, 0, stream>>>(
            qbf, WaT_c, attn_c, ba + (size_t)h0 * LV, LQ, LV, DMODEL,
            (long)LQ * DMODEL, 0L,               // A strides (b,h)
            0L, (long)LV * DMODEL,               // B strides (b,h)
            (long)LQ * LV, LV, (long)LV);        // C stride, ldc, bias_h stride

        // GEMM2: agg[z] = attn[z] @ vT[b]^T, M=2048 N=1024 K=2048
        gemm128<false, true><<<dim3(DMODEL / 128, LQ / 128, NH * 2), 256, 0, stream>>>(
            attn_c, vT, agg_c, nullptr, LQ, DMODEL, LV,
            (long)LQ * LV, (long)2 * LQ * LV,    // A strides (b,h): z = h*2+b
            (long)DMODEL * LV, 0L,               // B strides (b,h)
            (long)LQ * DMODEL, DMODEL, 0L);

        // LayerNorm in-place on this chunk
        ln_kernel<<<(NH * 2 * LQ) / 4, 256, 0, stream>>>(
            agg_c, gamma + (size_t)h0 * DMODEL, beta + (size_t)h0 * DMODEL);

        // projection + head concat -> d_out (f32)
        proj_kernel<<<dim3(LQ / 64, NH * 2), 256, 0, stream>>>(
            agg_c, WpT, bp, out, h0);
    }
}

// Round 3
// 840.771 us; speedup vs baseline: 1.1018x; 1.1018x over previous
//
#include <hip/hip_runtime.h>
#include <hip/hip_bf16.h>

typedef __attribute__((ext_vector_type(8))) short short8;   // 8 bf16 in 4 VGPRs
typedef __attribute__((ext_vector_type(4))) float f32x4;

#define N_HEAD 16
#define DMODEL 1024
#define LV 2048
#define LQ 2048
#define BATCH 2
#define HEAD_DIM 64

__device__ inline ushort f2bf(float f) {
    union { float f; unsigned u; } v; v.f = f;
    unsigned r = v.u + 0x7fffu + ((v.u >> 16) & 1u);   // RNE
    return (ushort)(r >> 16);
}
__device__ inline float bf2f(ushort h) {
    union { unsigned u; float f; } v; v.u = ((unsigned)h) << 16;
    return v.f;
}

// ---------------- cast f32 -> bf16 (same layout) ----------------
__global__ __launch_bounds__(256) void cast_bf16(const float* __restrict__ src,
                                                 ushort* __restrict__ dst, int n) {
    int i = (blockIdx.x * 256 + threadIdx.x) * 4;
    if (i < n) {
        float4 v = *(const float4*)(src + i);
        ushort4 o;
        o.x = f2bf(v.x); o.y = f2bf(v.y); o.z = f2bf(v.z); o.w = f2bf(v.w);
        *(ushort4*)(dst + i) = o;
    }
}

// ---------------- transpose + cast: src[z][R][C] f32 -> dst[z][C][R] bf16 ----
__global__ __launch_bounds__(256) void transpose_cast(const float* __restrict__ src,
                                                      ushort* __restrict__ dst,
                                                      int R, int C) {
    __shared__ float t[32][33];
    size_t zoff = (size_t)blockIdx.z * R * C;
    int c0 = blockIdx.x * 32, r0 = blockIdx.y * 32;
    int tx = threadIdx.x, ty = threadIdx.y;
#pragma unroll
    for (int i = 0; i < 4; ++i)
        t[ty + i * 8][tx] = src[zoff + (size_t)(r0 + ty + i * 8) * C + c0 + tx];
    __syncthreads();
#pragma unroll
    for (int i = 0; i < 4; ++i)
        dst[zoff + (size_t)(c0 + ty + i * 8) * R + r0 + tx] = f2bf(t[tx][ty + i * 8]);
}

// ---------------- 256x256 batched GEMM, 8-phase counted-vmcnt pipeline -------
// C[z] = (relu)(A[z] @ B[z]^T + bias).  A: MxK row-major bf16, B: NxK row-major
// (i.e. B^T).  BK=32, 4 LDS K-tile buffers (prefetch depth 3), 8 waves (2Mx4N),
// st_16x32 XOR-swizzled subtiled LDS ([rb][16][32] subtiles, byte^=((fr>>3)&1)<<5),
// written via pre-swizzled global source (rule #21), vmcnt(8) counted waits (T4),
// setprio around MFMA clusters (T5).
template <bool RELU>
__global__ __launch_bounds__(512, 2) void gemm256(
    const ushort* __restrict__ A, const ushort* __restrict__ B,
    ushort* __restrict__ Cout, const float* __restrict__ bias,
    int K,
    long sA_b, long sA_h, long sB_b, long sB_h, long sC_z, int ldc, long sBias_h)
{
    // [buf(4)][op(2)] x 16 KiB = 128 KiB.  op region: [half(2)][8 subtiles][1 KiB]
    __shared__ __align__(16) char smem[131072];

    const int z = blockIdx.z, b = z & 1, h = z >> 1;
    A += (size_t)b * sA_b + (size_t)h * sA_h;
    B += (size_t)b * sB_b + (size_t)h * sB_h;
    const float* biasp = bias ? bias + (size_t)h * sBias_h : nullptr;

    const int bm0 = blockIdx.y * 256;
    const int bn0 = blockIdx.x * 256;
    const int T = threadIdx.x;
    const int lane = T & 63, wid = T >> 6;
    const int wr = wid >> 2, wc = wid & 3;          // wave -> (2 x 4) grid
    const int fr = lane & 15, fq = lane >> 4;
    // byte offset of this lane's fragment within a 1 KiB subtile (swizzled read)
    const int laneoff = fr * 64 + ((fq * 16) ^ ((fr >> 3) << 5));

    // staging constants: thread T owns LDS bytes [T*16, T*16+16) of each half
    const int s_fr  = (T >> 2) & 15;
    const int s_csw = ((T & 3) * 16) ^ ((s_fr >> 3) << 5);   // pre-swizzled col
    const int s_rh  = ((T >> 6) << 4) + s_fr;                // row within half
    const ushort* gA = A + (size_t)(bm0 + s_rh) * K + (s_csw >> 1);
    const ushort* gB = B + (size_t)(bn0 + s_rh) * K + (s_csw >> 1);
    char* smc = smem;

    const int nt = K >> 5;      // K-tiles of 32

    auto stage = [&](int op, int half, int kt) {
        const ushort* src = (op ? gB : gA) + ((size_t)half * 128) * K + (size_t)kt * 32;
        char* dst = smc + (((kt & 3) * 2 + op) << 14) + (half << 13) + (T << 4);
        __builtin_amdgcn_global_load_lds(
            (const __attribute__((address_space(1))) void*)src,
            (__attribute__((address_space(3))) void*)dst, 16, 0, 0);
    };

    f32x4 acc[8][4];
#pragma unroll
    for (int m = 0; m < 8; ++m)
#pragma unroll
        for (int n = 0; n < 4; ++n)
#pragma unroll
            for (int j = 0; j < 4; ++j) acc[m][n][j] = 0.f;

    // prologue: stage tiles 0,1,2 into bufs 0,1,2 (12 loads/thread)
#pragma unroll
    for (int tt = 0; tt < 3; ++tt) {
        stage(0, 0, tt); stage(0, 1, tt);
        stage(1, 0, tt); stage(1, 1, tt);
    }
    asm volatile("s_waitcnt vmcnt(8)" ::: "memory");   // tile 0 landed
    __builtin_amdgcn_s_barrier();

    short8 a[8], bfr[4];
    for (int t = 0; t < nt; ++t) {
        const char* sA = smc + (((t & 3) * 2 + 0) << 14) + wr * 8192 + laneoff;
        const char* sB = smc + (((t & 3) * 2 + 1) << 14) + wc * 4096 + laneoff;

        // ---- phase 1: read A m0-3 + B n0-3; stage A halves of t+3 ----
#pragma unroll
        for (int m = 0; m < 4; ++m) a[m] = *(const short8*)(sA + m * 1024);
#pragma unroll
        for (int n = 0; n < 4; ++n) bfr[n] = *(const short8*)(sB + n * 1024);
        if (t + 3 < nt) { stage(0, 0, t + 3); stage(0, 1, t + 3); }
        asm volatile("" ::: "memory");
        __builtin_amdgcn_s_barrier();
        __builtin_amdgcn_s_setprio(1);
#pragma unroll
        for (int m = 0; m < 4; ++m)
#pragma unroll
            for (int n = 0; n < 4; ++n)
                acc[m][n] = __builtin_amdgcn_mfma_f32_16x16x32_bf16(
                    a[m], bfr[n], acc[m][n], 0, 0, 0);
        __builtin_amdgcn_s_setprio(0);
        asm volatile("" ::: "memory");
        __builtin_amdgcn_s_barrier();

        // ---- phase 2: read A m4-7; stage B halves of t+3; counted vmcnt ----
#pragma unroll
        for (int m = 4; m < 8; ++m) a[m] = *(const short8*)(sA + m * 1024);
        if (t + 3 < nt) { stage(1, 0, t + 3); stage(1, 1, t + 3); }
        // before next group reads tile t+1: tiles t+2,t+3 (4 loads each) may
        // remain in flight -> vmcnt(8); shrink at the tail.
        if (t < nt - 3)       asm volatile("s_waitcnt vmcnt(8)" ::: "memory");
        else if (t == nt - 3) asm volatile("s_waitcnt vmcnt(4)" ::: "memory");
        else if (t == nt - 2) asm volatile("s_waitcnt vmcnt(0)" ::: "memory");
        __builtin_amdgcn_s_barrier();
        __builtin_amdgcn_s_setprio(1);
#pragma unroll
        for (int m = 4; m < 8; ++m)
#pragma unroll
            for (int n = 0; n < 4; ++n)
                acc[m][n] = __builtin_amdgcn_mfma_f32_16x16x32_bf16(
                    a[m], bfr[n], acc[m][n], 0, 0, 0);
        __builtin_amdgcn_s_setprio(0);
        asm volatile("" ::: "memory");
        __builtin_amdgcn_s_barrier();
    }

    // epilogue: C[row = m*16 + fq*4 + j][col = n*16 + fr]  (m89/m91-verified)
    ushort* C = Cout + (size_t)z * sC_z;
    const int row0 = bm0 + wr * 128;
    const int col0 = bn0 + wc * 64;
#pragma unroll
    for (int n = 0; n < 4; ++n) {
        const int c = col0 + n * 16 + fr;
        const float bvv = biasp ? biasp[c] : 0.f;
#pragma unroll
        for (int m = 0; m < 8; ++m) {
            const int r = row0 + m * 16 + fq * 4;
#pragma unroll
            for (int j = 0; j < 4; ++j) {
                float val = acc[m][n][j] + bvv;
                if (RELU) val = fmaxf(val, 0.f);
                C[(size_t)(r + j) * ldc + c] = f2bf(val);
            }
        }
    }
}

// ---------------- in-place LayerNorm over last dim (1024) of agg bf16 --------
__global__ __launch_bounds__(256) void ln_kernel(ushort* __restrict__ agg,
                                                 const float* __restrict__ gamma,
                                                 const float* __restrict__ beta) {
    const int wid = threadIdx.x >> 6, lane = threadIdx.x & 63;
    const size_t row = (size_t)blockIdx.x * 4 + wid;
    const int h = (int)(row >> 12);
    ushort* p = agg + row * 1024 + lane * 16;
    short8 r0 = *(const short8*)p;
    short8 r1 = *(const short8*)(p + 8);
    float x[16];
#pragma unroll
    for (int j = 0; j < 8; ++j) { x[j] = bf2f((ushort)r0[j]); x[8 + j] = bf2f((ushort)r1[j]); }
    float s = 0.f, s2 = 0.f;
#pragma unroll
    for (int j = 0; j < 16; ++j) { s += x[j]; s2 += x[j] * x[j]; }
    for (int o = 1; o < 64; o <<= 1) {
        s  += __shfl_xor(s,  o, 64);
        s2 += __shfl_xor(s2, o, 64);
    }
    float mu  = s * (1.0f / 1024.0f);
    float var = s2 * (1.0f / 1024.0f) - mu * mu;
    float rs  = rsqrtf(fmaxf(var, 0.f) + 1e-5f);
    const float* g  = gamma + (size_t)h * 1024 + lane * 16;
    const float* bt = beta  + (size_t)h * 1024 + lane * 16;
    short8 o0, o1;
#pragma unroll
    for (int j = 0; j < 8; ++j) {
        o0[j] = (short)f2bf((x[j]     - mu) * rs * g[j]     + bt[j]);
        o1[j] = (short)f2bf((x[8 + j] - mu) * rs * g[8 + j] + bt[8 + j]);
    }
    *(short8*)p = o0;
    *(short8*)(p + 8) = o1;
}

// ---------------- projection: out[b][q][(h0+h)*64+e] = normed[z] @ WpT[h]^T + bp
__global__ __launch_bounds__(256) void proj_kernel(const ushort* __restrict__ normed,
                                                   const ushort* __restrict__ WpT,
                                                   const float* __restrict__ bp,
                                                   float* __restrict__ out,
                                                   int h_base) {
    const int z = blockIdx.y, b = z & 1, h = z >> 1;
    const int hg = h_base + h;
    const int wid = threadIdx.x >> 6, lane = threadIdx.x & 63;
    const int fr = lane & 15, fq = lane >> 4;
    const int m0 = (blockIdx.x * 4 + wid) * 16;

    const ushort* Abase = normed + ((size_t)z * 2048 + m0 + fr) * 1024 + fq * 8;
    const ushort* Bbase = WpT + (size_t)hg * 64 * 1024 + (size_t)fr * 1024 + fq * 8;

    f32x4 acc[4];
#pragma unroll
    for (int n = 0; n < 4; ++n)
#pragma unroll
        for (int j = 0; j < 4; ++j) acc[n][j] = 0.f;

    for (int kt = 0; kt < 32; ++kt) {
        short8 a = *(const short8*)(Abase + kt * 32);
#pragma unroll
        for (int n = 0; n < 4; ++n) {
            short8 bb = *(const short8*)(Bbase + n * 16 * 1024 + kt * 32);
            acc[n] = __builtin_amdgcn_mfma_f32_16x16x32_bf16(a, bb, acc[n], 0, 0, 0);
        }
    }
#pragma unroll
    for (int n = 0; n < 4; ++n) {
        int c = hg * 64 + n * 16 + fr;
        float bvv = bp[hg * 64 + n * 16 + fr];
#pragma unroll
        for (int j = 0; j < 4; ++j)
            out[(size_t)b * 2048 * 1024 + (size_t)(m0 + fq * 4 + j) * 1024 + c] =
                acc[n][j] + bvv;
    }
}

extern "C" void kernel_launch(void* const* d_in, const int* in_sizes, int n_in,
                              void* d_out, int out_size, void* d_ws, size_t ws_size,
                              hipStream_t stream) {
    const float* v     = (const float*)d_in[0];
    const float* q     = (const float*)d_in[1];
    const float* Wa    = (const float*)d_in[2];
    const float* ba    = (const float*)d_in[3];
    const float* gamma = (const float*)d_in[4];
    const float* beta  = (const float*)d_in[5];
    const float* Wp    = (const float*)d_in[6];
    const float* bp    = (const float*)d_in[7];
    float* out = (float*)d_out;

    const size_t MB = 1ull << 20;
    char* ws = (char*)d_ws;
    ushort* qbf = (ushort*)(ws);                 //  8 MiB
    ushort* vT  = (ushort*)(ws + 8 * MB);        //  8 MiB
    ushort* WpT = (ushort*)(ws + 16 * MB);       //  2 MiB
    int NH = 1;
    {
        const int cands[5] = {16, 8, 4, 2, 1};
        for (int i = 0; i < 5; ++i) {
            if ((size_t)(18 + 28 * cands[i]) * MB <= ws_size) { NH = cands[i]; break; }
        }
    }
    ushort* WaT_c  = (ushort*)(ws + 18 * MB);
    ushort* attn_c = (ushort*)(ws + (18 + (size_t)4 * NH) * MB);
    ushort* agg_c  = (ushort*)(ws + (18 + (size_t)20 * NH) * MB);

    dim3 tb(32, 8);
    cast_bf16<<<4096, 256, 0, stream>>>(q, qbf, BATCH * LQ * DMODEL);
    transpose_cast<<<dim3(DMODEL / 32, LV / 32, BATCH), tb, 0, stream>>>(v, vT, LV, DMODEL);
    transpose_cast<<<dim3(HEAD_DIM / 32, DMODEL / 32, N_HEAD), tb, 0, stream>>>(Wp, WpT, DMODEL, HEAD_DIM);

    for (int h0 = 0; h0 < N_HEAD; h0 += NH) {
        transpose_cast<<<dim3(LV / 32, DMODEL / 32, NH), tb, 0, stream>>>(
            Wa + (size_t)h0 * DMODEL * LV, WaT_c, DMODEL, LV);

        // GEMM1: attn[z] = relu(q[b] @ WaT[h]^T + ba[h0+h]), M=2048 N=2048 K=1024
        gemm256<true><<<dim3(LV / 256, LQ / 256, NH * 2), 512, 0, stream>>>(
            qbf, WaT_c, attn_c, ba + (size_t)h0 * LV, DMODEL,
            (long)LQ * DMODEL, 0L,
            0L, (long)LV * DMODEL,
            (long)LQ * LV, LV, (long)LV);

        // GEMM2: agg[z] = attn[z] @ vT[b]^T, M=2048 N=1024 K=2048
        gemm256<false><<<dim3(DMODEL / 256, LQ / 256, NH * 2), 512, 0, stream>>>(
            attn_c, vT, agg_c, nullptr, LV,
            (long)LQ * LV, (long)2 * LQ * LV,
            (long)DMODEL * LV, 0L,
            (long)LQ * DMODEL, DMODEL, 0L);

        ln_kernel<<<(NH * 2 * LQ) / 4, 256, 0, stream>>>(
            agg_c, gamma + (size_t)h0 * DMODEL, beta + (size_t)h0 * DMODEL);

        proj_kernel<<<dim3(LQ / 64, NH * 2), 256, 0, stream>>>(
            agg_c, WpT, bp, out, h0);
    }
}

// Round 4
// 830.961 us; speedup vs baseline: 1.1148x; 1.0118x over previous
//
#include <hip/hip_runtime.h>
#include <hip/hip_bf16.h>

typedef __attribute__((ext_vector_type(8))) short short8;   // 8 bf16 in 4 VGPRs
typedef __attribute__((ext_vector_type(4))) float f32x4;

#define N_HEAD 16
#define DMODEL 1024
#define LV 2048
#define LQ 2048
#define BATCH 2
#define HEAD_DIM 64

template <int N> struct IC { static constexpr int v = N; };

__device__ inline ushort f2bf(float f) {
    union { float f; unsigned u; } v; v.f = f;
    unsigned r = v.u + 0x7fffu + ((v.u >> 16) & 1u);   // RNE
    return (ushort)(r >> 16);
}
__device__ inline float bf2f(ushort h) {
    union { unsigned u; float f; } v; v.u = ((unsigned)h) << 16;
    return v.f;
}

// ---------------- cast f32 -> bf16 (same layout) ----------------
__global__ __launch_bounds__(256) void cast_bf16(const float* __restrict__ src,
                                                 ushort* __restrict__ dst, int n) {
    int i = (blockIdx.x * 256 + threadIdx.x) * 4;
    if (i < n) {
        float4 v = *(const float4*)(src + i);
        ushort4 o;
        o.x = f2bf(v.x); o.y = f2bf(v.y); o.z = f2bf(v.z); o.w = f2bf(v.w);
        *(ushort4*)(dst + i) = o;
    }
}

// ---------------- transpose + cast: src[z][R][C] f32 -> dst[z][C][R] bf16 ----
__global__ __launch_bounds__(256) void transpose_cast(const float* __restrict__ src,
                                                      ushort* __restrict__ dst,
                                                      int R, int C) {
    __shared__ float t[32][33];
    size_t zoff = (size_t)blockIdx.z * R * C;
    int c0 = blockIdx.x * 32, r0 = blockIdx.y * 32;
    int tx = threadIdx.x, ty = threadIdx.y;
#pragma unroll
    for (int i = 0; i < 4; ++i)
        t[ty + i * 8][tx] = src[zoff + (size_t)(r0 + ty + i * 8) * C + c0 + tx];
    __syncthreads();
#pragma unroll
    for (int i = 0; i < 4; ++i)
        dst[zoff + (size_t)(c0 + ty + i * 8) * R + r0 + tx] = f2bf(t[tx][ty + i * 8]);
}

// ---------------- 256x256 batched GEMM, counted-vmcnt pipeline ---------------
// C[z] = (relu)(A[z] @ B[z]^T + bias).  BK=32, 4 LDS K-tile buffers (prefetch
// depth 3), 8 waves (2Mx4N).  Compiler-proofed schedule: asm s_barrier (no
// implicit vmcnt drain), sched_barrier(0)-pinned MFMA clusters (rule #18),
// branch-free main loop + unrolled tail with constant vmcnt taper (T3+T4),
// setprio around MFMA (T5), st_16x32 XOR swizzle both-sides (T2, rule #21).
template <bool RELU>
__global__ __launch_bounds__(512, 2) void gemm256(
    const ushort* __restrict__ A, const ushort* __restrict__ B,
    ushort* __restrict__ Cout, const float* __restrict__ bias,
    int K,
    long sA_b, long sA_h, long sB_b, long sB_h, long sC_z, int ldc, long sBias_h)
{
    // [buf(4)][op(2)] x 16 KiB = 128 KiB.  op region: [half(2)][8 subtiles][1 KiB]
    __shared__ __align__(16) char smem[131072];

    const int z = blockIdx.z, b = z & 1, h = z >> 1;
    A += (size_t)b * sA_b + (size_t)h * sA_h;
    B += (size_t)b * sB_b + (size_t)h * sB_h;
    const float* biasp = bias ? bias + (size_t)h * sBias_h : nullptr;

    const int bm0 = blockIdx.y * 256;
    const int bn0 = blockIdx.x * 256;
    const int T = threadIdx.x;
    const int lane = T & 63, wid = T >> 6;
    const int wr = wid >> 2, wc = wid & 3;          // wave -> (2 x 4) grid
    const int fr = lane & 15, fq = lane >> 4;
    // byte offset of this lane's fragment within a 1 KiB subtile (swizzled read)
    const int laneoff = fr * 64 + ((fq * 16) ^ ((fr >> 3) << 5));

    // staging: thread T owns LDS bytes [T*16, T*16+16) of each 8 KiB half;
    // global source pre-swizzled so (linear LDS dest, swizzled read) match.
    const int s_fr  = (T >> 2) & 15;
    const int s_csw = ((T & 3) * 16) ^ ((s_fr >> 3) << 5);   // pre-swizzled col
    const int s_rh  = ((T >> 6) << 4) + s_fr;                // row within half
    const ushort* gA = A + (size_t)(bm0 + s_rh) * K + (s_csw >> 1);
    const ushort* gB = B + (size_t)(bn0 + s_rh) * K + (s_csw >> 1);
    char* smc = smem;

    const int nt = K >> 5;      // K-tiles of 32

    auto stage = [&](int op, int half, int kt) {
        const ushort* src = (op ? gB : gA) + ((size_t)half * 128) * K + (size_t)kt * 32;
        char* dst = smc + (((kt & 3) * 2 + op) << 14) + (half << 13) + (T << 4);
        __builtin_amdgcn_global_load_lds(
            (const __attribute__((address_space(1))) void*)src,
            (__attribute__((address_space(3))) void*)dst, 16, 0, 0);
    };

    f32x4 acc[8][4];
#pragma unroll
    for (int m = 0; m < 8; ++m)
#pragma unroll
        for (int n = 0; n < 4; ++n)
#pragma unroll
            for (int j = 0; j < 4; ++j) acc[m][n][j] = 0.f;

    // prologue: stage tiles 0,1,2 into bufs 0,1,2 (12 loads/thread)
#pragma unroll
    for (int tt = 0; tt < 3; ++tt) {
        stage(0, 0, tt); stage(0, 1, tt);
        stage(1, 0, tt); stage(1, 1, tt);
    }
    asm volatile("s_waitcnt vmcnt(8)" ::: "memory");   // tile 0 landed
    asm volatile("s_barrier" ::: "memory");

    // one K-tile: DS.v = stage tile t+3?  VM.v = vmcnt taper (-1 = none)
    auto tile = [&](int t, auto DS, auto VM) {
        constexpr int do_stage = decltype(DS)::v;
        constexpr int vm = decltype(VM)::v;
        const char* sA = smc + (((t & 3) * 2 + 0) << 14) + wr * 8192 + laneoff;
        const char* sB = smc + (((t & 3) * 2 + 1) << 14) + wc * 4096 + laneoff;
        short8 a[8], bfr[4];

        // ---- phase 1: read A m0-3 + B n0-3; stage A halves of t+3 ----
#pragma unroll
        for (int m = 0; m < 4; ++m) a[m] = *(const short8*)(sA + m * 1024);
#pragma unroll
        for (int n = 0; n < 4; ++n) bfr[n] = *(const short8*)(sB + n * 1024);
        if constexpr (do_stage) { stage(0, 0, t + 3); stage(0, 1, t + 3); }
        asm volatile("s_barrier" ::: "memory");
        __builtin_amdgcn_sched_barrier(0);
        __builtin_amdgcn_s_setprio(1);
#pragma unroll
        for (int m = 0; m < 4; ++m)
#pragma unroll
            for (int n = 0; n < 4; ++n)
                acc[m][n] = __builtin_amdgcn_mfma_f32_16x16x32_bf16(
                    a[m], bfr[n], acc[m][n], 0, 0, 0);
        __builtin_amdgcn_s_setprio(0);
        __builtin_amdgcn_sched_barrier(0);
        asm volatile("s_barrier" ::: "memory");

        // ---- phase 2: read A m4-7; stage B halves of t+3; counted vmcnt ----
#pragma unroll
        for (int m = 4; m < 8; ++m) a[m] = *(const short8*)(sA + m * 1024);
        if constexpr (do_stage) { stage(1, 0, t + 3); stage(1, 1, t + 3); }
        if constexpr (vm == 8)      asm volatile("s_waitcnt vmcnt(8)" ::: "memory");
        else if constexpr (vm == 4) asm volatile("s_waitcnt vmcnt(4)" ::: "memory");
        else if constexpr (vm == 0) asm volatile("s_waitcnt vmcnt(0)" ::: "memory");
        asm volatile("s_barrier" ::: "memory");
        __builtin_amdgcn_sched_barrier(0);
        __builtin_amdgcn_s_setprio(1);
#pragma unroll
        for (int m = 4; m < 8; ++m)
#pragma unroll
            for (int n = 0; n < 4; ++n)
                acc[m][n] = __builtin_amdgcn_mfma_f32_16x16x32_bf16(
                    a[m], bfr[n], acc[m][n], 0, 0, 0);
        __builtin_amdgcn_s_setprio(0);
        __builtin_amdgcn_sched_barrier(0);
        asm volatile("s_barrier" ::: "memory");
    };

    // branch-free steady state, then 3-tile tail with vmcnt taper 8->4->0
    for (int t = 0; t < nt - 3; ++t) tile(t, IC<1>{}, IC<8>{});
    tile(nt - 3, IC<0>{}, IC<4>{});
    tile(nt - 2, IC<0>{}, IC<0>{});
    tile(nt - 1, IC<0>{}, IC<-1>{});

    // epilogue: C[row = m*16 + fq*4 + j][col = n*16 + fr]  (m89/m91-verified)
    ushort* C = Cout + (size_t)z * sC_z;
    const int row0 = bm0 + wr * 128;
    const int col0 = bn0 + wc * 64;
#pragma unroll
    for (int n = 0; n < 4; ++n) {
        const int c = col0 + n * 16 + fr;
        const float bvv = biasp ? biasp[c] : 0.f;
#pragma unroll
        for (int m = 0; m < 8; ++m) {
            const int r = row0 + m * 16 + fq * 4;
#pragma unroll
            for (int j = 0; j < 4; ++j) {
                float val = acc[m][n][j] + bvv;
                if (RELU) val = fmaxf(val, 0.f);
                C[(size_t)(r + j) * ldc + c] = f2bf(val);
            }
        }
    }
}

// ---------------- in-place LayerNorm over last dim (1024) of agg bf16 --------
__global__ __launch_bounds__(256) void ln_kernel(ushort* __restrict__ agg,
                                                 const float* __restrict__ gamma,
                                                 const float* __restrict__ beta) {
    const int wid = threadIdx.x >> 6, lane = threadIdx.x & 63;
    const size_t row = (size_t)blockIdx.x * 4 + wid;
    const int h = (int)(row >> 12);
    ushort* p = agg + row * 1024 + lane * 16;
    short8 r0 = *(const short8*)p;
    short8 r1 = *(const short8*)(p + 8);
    float x[16];
#pragma unroll
    for (int j = 0; j < 8; ++j) { x[j] = bf2f((ushort)r0[j]); x[8 + j] = bf2f((ushort)r1[j]); }
    float s = 0.f, s2 = 0.f;
#pragma unroll
    for (int j = 0; j < 16; ++j) { s += x[j]; s2 += x[j] * x[j]; }
    for (int o = 1; o < 64; o <<= 1) {
        s  += __shfl_xor(s,  o, 64);
        s2 += __shfl_xor(s2, o, 64);
    }
    float mu  = s * (1.0f / 1024.0f);
    float var = s2 * (1.0f / 1024.0f) - mu * mu;
    float rs  = rsqrtf(fmaxf(var, 0.f) + 1e-5f);
    const float* g  = gamma + (size_t)h * 1024 + lane * 16;
    const float* bt = beta  + (size_t)h * 1024 + lane * 16;
    short8 o0, o1;
#pragma unroll
    for (int j = 0; j < 8; ++j) {
        o0[j] = (short)f2bf((x[j]     - mu) * rs * g[j]     + bt[j]);
        o1[j] = (short)f2bf((x[8 + j] - mu) * rs * g[8 + j] + bt[8 + j]);
    }
    *(short8*)p = o0;
    *(short8*)(p + 8) = o1;
}

// ---------------- projection: out[b][q][(h0+h)*64+e] = normed[z] @ WpT[h]^T + bp
__global__ __launch_bounds__(256) void proj_kernel(const ushort* __restrict__ normed,
                                                   const ushort* __restrict__ WpT,
                                                   const float* __restrict__ bp,
                                                   float* __restrict__ out,
                                                   int h_base) {
    const int z = blockIdx.y, b = z & 1, h = z >> 1;
    const int hg = h_base + h;
    const int wid = threadIdx.x >> 6, lane = threadIdx.x & 63;
    const int fr = lane & 15, fq = lane >> 4;
    const int m0 = (blockIdx.x * 4 + wid) * 16;

    const ushort* Abase = normed + ((size_t)z * 2048 + m0 + fr) * 1024 + fq * 8;
    const ushort* Bbase = WpT + (size_t)hg * 64 * 1024 + (size_t)fr * 1024 + fq * 8;

    f32x4 acc[4];
#pragma unroll
    for (int n = 0; n < 4; ++n)
#pragma unroll
        for (int j = 0; j < 4; ++j) acc[n][j] = 0.f;

    for (int kt = 0; kt < 32; ++kt) {
        short8 a = *(const short8*)(Abase + kt * 32);
#pragma unroll
        for (int n = 0; n < 4; ++n) {
            short8 bb = *(const short8*)(Bbase + n * 16 * 1024 + kt * 32);
            acc[n] = __builtin_amdgcn_mfma_f32_16x16x32_bf16(a, bb, acc[n], 0, 0, 0);
        }
    }
#pragma unroll
    for (int n = 0; n < 4; ++n) {
        int c = hg * 64 + n * 16 + fr;
        float bvv = bp[hg * 64 + n * 16 + fr];
#pragma unroll
        for (int j = 0; j < 4; ++j)
            out[(size_t)b * 2048 * 1024 + (size_t)(m0 + fq * 4 + j) * 1024 + c] =
                acc[n][j] + bvv;
    }
}

extern "C" void kernel_launch(void* const* d_in, const int* in_sizes, int n_in,
                              void* d_out, int out_size, void* d_ws, size_t ws_size,
                              hipStream_t stream) {
    const float* v     = (const float*)d_in[0];
    const float* q     = (const float*)d_in[1];
    const float* Wa    = (const float*)d_in[2];
    const float* ba    = (const float*)d_in[3];
    const float* gamma = (const float*)d_in[4];
    const float* beta  = (const float*)d_in[5];
    const float* Wp    = (const float*)d_in[6];
    const float* bp    = (const float*)d_in[7];
    float* out = (float*)d_out;

    const size_t MB = 1ull << 20;
    char* ws = (char*)d_ws;
    ushort* qbf = (ushort*)(ws);                 //  8 MiB
    ushort* vT  = (ushort*)(ws + 8 * MB);        //  8 MiB
    ushort* WpT = (ushort*)(ws + 16 * MB);       //  2 MiB
    int NH = 1;
    {
        const int cands[5] = {16, 8, 4, 2, 1};
        for (int i = 0; i < 5; ++i) {
            if ((size_t)(18 + 28 * cands[i]) * MB <= ws_size) { NH = cands[i]; break; }
        }
    }
    ushort* WaT_c  = (ushort*)(ws + 18 * MB);
    ushort* attn_c = (ushort*)(ws + (18 + (size_t)4 * NH) * MB);
    ushort* agg_c  = (ushort*)(ws + (18 + (size_t)20 * NH) * MB);

    dim3 tb(32, 8);
    cast_bf16<<<4096, 256, 0, stream>>>(q, qbf, BATCH * LQ * DMODEL);
    transpose_cast<<<dim3(DMODEL / 32, LV / 32, BATCH), tb, 0, stream>>>(v, vT, LV, DMODEL);
    transpose_cast<<<dim3(HEAD_DIM / 32, DMODEL / 32, N_HEAD), tb, 0, stream>>>(Wp, WpT, DMODEL, HEAD_DIM);

    for (int h0 = 0; h0 < N_HEAD; h0 += NH) {
        transpose_cast<<<dim3(LV / 32, DMODEL / 32, NH), tb, 0, stream>>>(
            Wa + (size_t)h0 * DMODEL * LV, WaT_c, DMODEL, LV);

        // GEMM1: attn[z] = relu(q[b] @ WaT[h]^T + ba[h0+h]), M=2048 N=2048 K=1024
        gemm256<true><<<dim3(LV / 256, LQ / 256, NH * 2), 512, 0, stream>>>(
            qbf, WaT_c, attn_c, ba + (size_t)h0 * LV, DMODEL,
            (long)LQ * DMODEL, 0L,
            0L, (long)LV * DMODEL,
            (long)LQ * LV, LV, (long)LV);

        // GEMM2: agg[z] = attn[z] @ vT[b]^T, M=2048 N=1024 K=2048
        gemm256<false><<<dim3(DMODEL / 256, LQ / 256, NH * 2), 512, 0, stream>>>(
            attn_c, vT, agg_c, nullptr, LV,
            (long)LQ * LV, (long)2 * LQ * LV,
            (long)DMODEL * LV, 0L,
            (long)LQ * DMODEL, DMODEL, 0L);

        ln_kernel<<<(NH * 2 * LQ) / 4, 256, 0, stream>>>(
            agg_c, gamma + (size_t)h0 * DMODEL, beta + (size_t)h0 * DMODEL);

        proj_kernel<<<dim3(LQ / 64, NH * 2), 256, 0, stream>>>(
            agg_c, WpT, bp, out, h0);
    }
}